// Round 1
// baseline (1309.120 us; speedup 1.0000x reference)
//
#include <hip/hip_runtime.h>

#define T_DIM 2048
#define B_DIM 32
#define H_DIM 1024
#define I_DIM 1024
#define M_DIM (T_DIM * B_DIM)      // 65536
#define K_DIM I_DIM                // 1024
#define N_DIM H_DIM                // 1024
#define YS_ELEMS (M_DIM * H_DIM)   // 67108864 (also == x elem count)
#define BH (B_DIM * H_DIM)         // 32768

typedef unsigned short u16;
typedef __attribute__((ext_vector_type(8))) short bf16x8;  // 8 bf16 = 4 VGPRs
typedef __attribute__((ext_vector_type(4))) float f32x4;   // MFMA 16x16 acc

__device__ __forceinline__ u16 f2bf(float f) {
  union { float f; unsigned u; } c; c.f = f;
  return (u16)((c.u + 0x7fffu + ((c.u >> 16) & 1u)) >> 16);  // RTNE
}
__device__ __forceinline__ float bf2f(u16 s) {
  union { float f; unsigned u; } c; c.u = ((unsigned)s) << 16;
  return c.f;
}

// fp32 -> bf16 hi/lo split (x = hi + lo + O(2^-18))
__global__ __launch_bounds__(256) void split_kernel(
    const float* __restrict__ x, u16* __restrict__ hi, u16* __restrict__ lo, int n4) {
  int i = blockIdx.x * 256 + threadIdx.x;
  if (i >= n4) return;
  float4 v = ((const float4*)x)[i];
  ushort4 h, l;
  h.x = f2bf(v.x); l.x = f2bf(v.x - bf2f(h.x));
  h.y = f2bf(v.y); l.y = f2bf(v.y - bf2f(h.y));
  h.z = f2bf(v.z); l.z = f2bf(v.z - bf2f(h.z));
  h.w = f2bf(v.w); l.w = f2bf(v.w - bf2f(h.w));
  ((ushort4*)hi)[i] = h;
  ((ushort4*)lo)[i] = l;
}

// async global->LDS, 16B per lane; LDS dst = wave-uniform base + lane*16
__device__ __forceinline__ void gload_lds16(const u16* g, u16* l) {
  __builtin_amdgcn_global_load_lds(
      (const __attribute__((address_space(1))) void*)g,
      (__attribute__((address_space(3))) void*)l, 16, 0, 0);
}

// C[m,n] = sum_k (Ah+Al)[m,k]*(Bh+Bl)[n,k], 3-term split, fp32 out.
// Block tile 128x128, 4 waves 2x2 of 64x64, BK=32.
__global__ __launch_bounds__(256, 2) void gemm_split(
    const u16* __restrict__ Ah, const u16* __restrict__ Al,
    const u16* __restrict__ Bh, const u16* __restrict__ Bl,
    float* __restrict__ C) {
  // each tile: 128 rows x 32 k bf16, row stride 64B (global_load_lds needs linear layout)
  __shared__ u16 sAh[128 * 32], sAl[128 * 32], sBh[128 * 32], sBl[128 * 32];

  // swizzle: group of 32 m-tiles x all 8 n-tiles (256 blocks) so A hits L2/L3
  const int bid = blockIdx.x;
  const int grp = bid >> 8;
  const int r = bid & 255;
  const int n0 = (r >> 5) * 128;
  const int m0 = ((grp << 5) + (r & 31)) * 128;

  const int tid = threadIdx.x;
  const int wave = tid >> 6;
  const int lane = tid & 63;

  // staging map: thread stages 16B segment s=tid (rows 0..63) and s=tid+256 (rows 64..127)
  const int srow = tid >> 2;           // 0..63
  const int skofs = (tid & 3) * 8;     // bf16 elems within row

  const u16* gAh0 = Ah + (size_t)(m0 + srow) * K_DIM + skofs;
  const u16* gAh1 = gAh0 + (size_t)64 * K_DIM;
  const u16* gAl0 = Al + (size_t)(m0 + srow) * K_DIM + skofs;
  const u16* gAl1 = gAl0 + (size_t)64 * K_DIM;
  const u16* gBh0 = Bh + (size_t)(n0 + srow) * K_DIM + skofs;
  const u16* gBh1 = gBh0 + (size_t)64 * K_DIM;
  const u16* gBl0 = Bl + (size_t)(n0 + srow) * K_DIM + skofs;
  const u16* gBl1 = gBl0 + (size_t)64 * K_DIM;

  const int wofs = wave * 512;         // u16 offset of this wave's staging slice

  const int wm = (wave & 1) * 64;
  const int wn = (wave >> 1) * 64;
  const int fr = lane & 15;            // fragment row (m or n)
  const int kq = (lane >> 4) * 8;      // k offset within fragment

  f32x4 acc[4][4] = {};

  for (int k0 = 0; k0 < K_DIM; k0 += 32) {
    __syncthreads();  // previous iter's ds_reads done before overwrite
    gload_lds16(gAh0 + k0, sAh + wofs);
    gload_lds16(gAh1 + k0, sAh + wofs + 2048);
    gload_lds16(gAl0 + k0, sAl + wofs);
    gload_lds16(gAl1 + k0, sAl + wofs + 2048);
    gload_lds16(gBh0 + k0, sBh + wofs);
    gload_lds16(gBh1 + k0, sBh + wofs + 2048);
    gload_lds16(gBl0 + k0, sBl + wofs);
    gload_lds16(gBl1 + k0, sBl + wofs + 2048);
    __syncthreads();  // barrier drains vmcnt -> LDS visible

    bf16x8 ah[4], al[4], bh[4], bl[4];
#pragma unroll
    for (int i = 0; i < 4; ++i) {
      ah[i] = *(const bf16x8*)(sAh + (wm + i * 16 + fr) * 32 + kq);
      al[i] = *(const bf16x8*)(sAl + (wm + i * 16 + fr) * 32 + kq);
      bh[i] = *(const bf16x8*)(sBh + (wn + i * 16 + fr) * 32 + kq);
      bl[i] = *(const bf16x8*)(sBl + (wn + i * 16 + fr) * 32 + kq);
    }
#pragma unroll
    for (int i = 0; i < 4; ++i) {
#pragma unroll
      for (int j = 0; j < 4; ++j) {
        acc[i][j] = __builtin_amdgcn_mfma_f32_16x16x32_bf16(ah[i], bh[j], acc[i][j], 0, 0, 0);
        acc[i][j] = __builtin_amdgcn_mfma_f32_16x16x32_bf16(ah[i], bl[j], acc[i][j], 0, 0, 0);
        acc[i][j] = __builtin_amdgcn_mfma_f32_16x16x32_bf16(al[i], bh[j], acc[i][j], 0, 0, 0);
      }
    }
  }

  // C/D layout (m89-verified): col = lane&15, row = (lane>>4)*4 + reg
  const int rq = (lane >> 4) * 4;
#pragma unroll
  for (int i = 0; i < 4; ++i) {
#pragma unroll
    for (int j = 0; j < 4; ++j) {
      const int col = n0 + wn + j * 16 + fr;
      const size_t rowb = (size_t)(m0 + wm + i * 16 + rq);
#pragma unroll
      for (int rr = 0; rr < 4; ++rr)
        C[(rowb + rr) * N_DIM + col] = acc[i][j][rr];
    }
  }
}

// in-place sequential scan over T: h = relu(pre + bias + u*h)
// one thread per (b,h) channel; 16-deep double-buffered prefetch
__global__ __launch_bounds__(256) void scan_kernel(
    float* __restrict__ yio, float* __restrict__ hlast,
    const float* __restrict__ bih, const float* __restrict__ bhh,
    const float* __restrict__ u) {
  const int j = blockIdx.x * 256 + threadIdx.x;  // 0..BH-1
  const int hc = j & (H_DIM - 1);
  const float uu = u[hc];
  const float bias = bih[hc] + bhh[hc];
  float h = 0.f;
  float* p = yio + j;
  const int S = BH;
  constexpr int UN = 16;
  float buf[2][UN];
#pragma unroll
  for (int i = 0; i < UN; ++i) buf[0][i] = p[(size_t)i * S];
  int cur = 0;
  for (int t0 = 0; t0 < T_DIM; t0 += UN) {
    const int nxt = cur ^ 1;
    if (t0 + UN < T_DIM) {
#pragma unroll
      for (int i = 0; i < UN; ++i) buf[nxt][i] = p[(size_t)(t0 + UN + i) * S];
    }
#pragma unroll
    for (int i = 0; i < UN; ++i) {
      float v = buf[cur][i] + bias + uu * h;
      h = v > 0.f ? v : 0.f;
      p[(size_t)(t0 + i) * S] = h;
    }
    cur = nxt;
  }
  hlast[j] = h;
}

extern "C" void kernel_launch(void* const* d_in, const int* in_sizes, int n_in,
                              void* d_out, int out_size, void* d_ws, size_t ws_size,
                              hipStream_t stream) {
  const float* x   = (const float*)d_in[0];
  const float* w   = (const float*)d_in[1];
  const float* bih = (const float*)d_in[2];
  const float* bhh = (const float*)d_in[3];
  const float* u   = (const float*)d_in[4];
  float* out = (float*)d_out;

  // workspace layout: x_hi | x_lo | w_hi | w_lo  (~260 MiB)
  u16* xh = (u16*)d_ws;
  u16* xl = xh + (size_t)YS_ELEMS;
  u16* wh = xl + (size_t)YS_ELEMS;
  u16* wl = wh + (size_t)(H_DIM * I_DIM);

  split_kernel<<<YS_ELEMS / 4 / 256, 256, 0, stream>>>(x, xh, xl, YS_ELEMS / 4);
  split_kernel<<<(H_DIM * I_DIM) / 4 / 256, 256, 0, stream>>>(w, wh, wl, (H_DIM * I_DIM) / 4);
  gemm_split<<<(M_DIM / 128) * (N_DIM / 128), 256, 0, stream>>>(xh, xl, wh, wl, out);
  scan_kernel<<<BH / 256, 256, 0, stream>>>(out, out + (size_t)YS_ELEMS, bih, bhh, u);
}

// Round 2
// 930.600 us; speedup vs baseline: 1.4067x; 1.4067x over previous
//
#include <hip/hip_runtime.h>

#define T_DIM 2048
#define B_DIM 32
#define H_DIM 1024
#define I_DIM 1024
#define M_DIM (T_DIM * B_DIM)      // 65536
#define K_DIM I_DIM                // 1024
#define N_DIM H_DIM                // 1024
#define YS_ELEMS (M_DIM * H_DIM)   // 67108864 (also == x elem count)
#define BH (B_DIM * H_DIM)         // 32768

typedef unsigned short u16;
typedef __attribute__((ext_vector_type(8))) short bf16x8;   // 8 bf16 = 4 VGPRs
typedef __attribute__((ext_vector_type(16))) float f32x16;  // MFMA 32x32 acc

__device__ __forceinline__ u16 f2bf(float f) {
  union { float f; unsigned u; } c; c.f = f;
  return (u16)((c.u + 0x7fffu + ((c.u >> 16) & 1u)) >> 16);  // RTNE
}
__device__ __forceinline__ float bf2f(u16 s) {
  union { float f; unsigned u; } c; c.u = ((unsigned)s) << 16;
  return c.f;
}

// fp32 -> bf16 hi/lo split (x = hi + lo + O(2^-18))
__global__ __launch_bounds__(256) void split_kernel(
    const float* __restrict__ x, u16* __restrict__ hi, u16* __restrict__ lo, int n4) {
  int i = blockIdx.x * 256 + threadIdx.x;
  if (i >= n4) return;
  float4 v = ((const float4*)x)[i];
  ushort4 h, l;
  h.x = f2bf(v.x); l.x = f2bf(v.x - bf2f(h.x));
  h.y = f2bf(v.y); l.y = f2bf(v.y - bf2f(h.y));
  h.z = f2bf(v.z); l.z = f2bf(v.z - bf2f(h.z));
  h.w = f2bf(v.w); l.w = f2bf(v.w - bf2f(h.w));
  ((ushort4*)hi)[i] = h;
  ((ushort4*)lo)[i] = l;
}

// async global->LDS, 16B per lane; LDS dst = wave-uniform base + lane*16
__device__ __forceinline__ void gload_lds16(const u16* g, u16* l) {
  __builtin_amdgcn_global_load_lds(
      (const __attribute__((address_space(1))) void*)g,
      (__attribute__((address_space(3))) void*)l, 16, 0, 0);
}

// C[m,n] = sum_k (Ah+Al)[m,k]*(Bh+Bl)[n,k], 3-term split, fp32 out.
// Block tile 128x128, 4 waves 2x2 of 64x64, each wave 2x2 of 32x32 MFMA, BK=32.
__global__ __launch_bounds__(256, 2) void gemm_split(
    const u16* __restrict__ Ah, const u16* __restrict__ Al,
    const u16* __restrict__ Bh, const u16* __restrict__ Bl,
    float* __restrict__ C) {
  // each tile: 128 rows x 32 k bf16, row-linear (global_load_lds needs linear layout)
  __shared__ u16 sAh[128 * 32], sAl[128 * 32], sBh[128 * 32], sBl[128 * 32];

  // swizzle: group of 32 m-tiles x all 8 n-tiles (256 blocks) so A hits L2/L3
  const int bid = blockIdx.x;
  const int grp = bid >> 8;
  const int r = bid & 255;
  const int n0 = (r >> 5) * 128;
  const int m0 = ((grp << 5) + (r & 31)) * 128;

  const int tid = threadIdx.x;
  const int wave = tid >> 6;
  const int lane = tid & 63;

  // staging map: thread stages 16B at row tid>>2, kofs (tid&3)*8 (+64 rows for 2nd call)
  const int srow = tid >> 2;
  const int skofs = (tid & 3) * 8;

  const u16* gAh0 = Ah + (size_t)(m0 + srow) * K_DIM + skofs;
  const u16* gAh1 = gAh0 + (size_t)64 * K_DIM;
  const u16* gAl0 = Al + (size_t)(m0 + srow) * K_DIM + skofs;
  const u16* gAl1 = gAl0 + (size_t)64 * K_DIM;
  const u16* gBh0 = Bh + (size_t)(n0 + srow) * K_DIM + skofs;
  const u16* gBh1 = gBh0 + (size_t)64 * K_DIM;
  const u16* gBl0 = Bl + (size_t)(n0 + srow) * K_DIM + skofs;
  const u16* gBl1 = gBl0 + (size_t)64 * K_DIM;

  const int wofs = wave * 512;  // u16 offset of this wave's staging slice

  const int wm = (wave & 1) * 64;
  const int wn = (wave >> 1) * 64;
  const int cl = lane & 31;         // row within 32-tile (m or n)
  const int kh8 = (lane >> 5) * 8;  // k offset within 16-k step

  f32x16 acc[2][2] = {};

  for (int k0 = 0; k0 < K_DIM; k0 += 32) {
    __syncthreads();  // previous iter's ds_reads done before overwrite
    gload_lds16(gAh0 + k0, sAh + wofs);
    gload_lds16(gAh1 + k0, sAh + wofs + 2048);
    gload_lds16(gAl0 + k0, sAl + wofs);
    gload_lds16(gAl1 + k0, sAl + wofs + 2048);
    gload_lds16(gBh0 + k0, sBh + wofs);
    gload_lds16(gBh1 + k0, sBh + wofs + 2048);
    gload_lds16(gBl0 + k0, sBl + wofs);
    gload_lds16(gBl1 + k0, sBl + wofs + 2048);
    __syncthreads();  // barrier drains vmcnt -> LDS visible

    // A/B operand layout (32x32x16): m|n = lane&31, k = (lane>>5)*8 + idx
    bf16x8 ah[2][2], al[2][2], bh[2][2], bl[2][2];  // [tile][kstep]
#pragma unroll
    for (int i = 0; i < 2; ++i)
#pragma unroll
      for (int s = 0; s < 2; ++s) {
        ah[i][s] = *(const bf16x8*)(sAh + (wm + i * 32 + cl) * 32 + s * 16 + kh8);
        al[i][s] = *(const bf16x8*)(sAl + (wm + i * 32 + cl) * 32 + s * 16 + kh8);
        bh[i][s] = *(const bf16x8*)(sBh + (wn + i * 32 + cl) * 32 + s * 16 + kh8);
        bl[i][s] = *(const bf16x8*)(sBl + (wn + i * 32 + cl) * 32 + s * 16 + kh8);
      }
#pragma unroll
    for (int s = 0; s < 2; ++s)
#pragma unroll
      for (int i = 0; i < 2; ++i)
#pragma unroll
        for (int j = 0; j < 2; ++j) {
          acc[i][j] = __builtin_amdgcn_mfma_f32_32x32x16_bf16(ah[i][s], bh[j][s], acc[i][j], 0, 0, 0);
          acc[i][j] = __builtin_amdgcn_mfma_f32_32x32x16_bf16(ah[i][s], bl[j][s], acc[i][j], 0, 0, 0);
          acc[i][j] = __builtin_amdgcn_mfma_f32_32x32x16_bf16(al[i][s], bh[j][s], acc[i][j], 0, 0, 0);
        }
  }

  // C/D layout (m74/m101): col = lane&31, row = (reg&3) + 8*(reg>>2) + 4*(lane>>5)
  const int rh = (lane >> 5) * 4;
#pragma unroll
  for (int i = 0; i < 2; ++i)
#pragma unroll
    for (int j = 0; j < 2; ++j) {
      const int col = n0 + wn + j * 32 + cl;
      const size_t rb = (size_t)(m0 + wm + i * 32 + rh);
#pragma unroll
      for (int rr = 0; rr < 16; ++rr)
        C[(rb + (rr & 3) + 8 * (rr >> 2)) * N_DIM + col] = acc[i][j][rr];
    }
}

// in-place sequential scan over T: h = relu(pre + bias + u*h)
// one thread per (b,h) channel; two register buffers, manually 2x-unrolled
// outer loop so ALL buffer indices are compile-time constant (register-resident).
__global__ __launch_bounds__(64) void scan_kernel(
    float* __restrict__ yio, float* __restrict__ hlast,
    const float* __restrict__ bih, const float* __restrict__ bhh,
    const float* __restrict__ u) {
  const int j = blockIdx.x * 64 + threadIdx.x;  // 0..BH-1
  const int hc = j & (H_DIM - 1);
  const float uu = u[hc];
  const float bias = bih[hc] + bhh[hc];
  float h = 0.f;
  float* p = yio + j;
  constexpr int UN = 32;
  float bufA[UN], bufB[UN];
#pragma unroll
  for (int i = 0; i < UN; ++i) bufA[i] = p[(size_t)i * BH];
#pragma unroll 1
  for (int t0 = 0; t0 < T_DIM; t0 += 2 * UN) {
    // prefetch B chunk (t0+UN .. t0+2UN): always in range (t0 <= T-2UN)
#pragma unroll
    for (int i = 0; i < UN; ++i) bufB[i] = p[(size_t)(t0 + UN + i) * BH];
    // compute+store A chunk
#pragma unroll
    for (int i = 0; i < UN; ++i) {
      float v = bufA[i] + bias + uu * h;
      h = v > 0.f ? v : 0.f;
      p[(size_t)(t0 + i) * BH] = h;
    }
    // prefetch next A chunk
    if (t0 + 2 * UN < T_DIM) {
#pragma unroll
      for (int i = 0; i < UN; ++i) bufA[i] = p[(size_t)(t0 + 2 * UN + i) * BH];
    }
    // compute+store B chunk
#pragma unroll
    for (int i = 0; i < UN; ++i) {
      float v = bufB[i] + bias + uu * h;
      h = v > 0.f ? v : 0.f;
      p[(size_t)(t0 + UN + i) * BH] = h;
    }
  }
  hlast[j] = h;
}

extern "C" void kernel_launch(void* const* d_in, const int* in_sizes, int n_in,
                              void* d_out, int out_size, void* d_ws, size_t ws_size,
                              hipStream_t stream) {
  const float* x   = (const float*)d_in[0];
  const float* w   = (const float*)d_in[1];
  const float* bih = (const float*)d_in[2];
  const float* bhh = (const float*)d_in[3];
  const float* u   = (const float*)d_in[4];
  float* out = (float*)d_out;

  // workspace layout: x_hi | x_lo | w_hi | w_lo  (~260 MiB)
  u16* xh = (u16*)d_ws;
  u16* xl = xh + (size_t)YS_ELEMS;
  u16* wh = xl + (size_t)YS_ELEMS;
  u16* wl = wh + (size_t)(H_DIM * I_DIM);

  split_kernel<<<YS_ELEMS / 4 / 256, 256, 0, stream>>>(x, xh, xl, YS_ELEMS / 4);
  split_kernel<<<(H_DIM * I_DIM) / 4 / 256, 256, 0, stream>>>(w, wh, wl, (H_DIM * I_DIM) / 4);
  gemm_split<<<(M_DIM / 128) * (N_DIM / 128), 256, 0, stream>>>(xh, xl, wh, wl, out);
  scan_kernel<<<BH / 64, 64, 0, stream>>>(out, out + (size_t)YS_ELEMS, bih, bhh, u);
}